// Round 1
// baseline (847.024 us; speedup 1.0000x reference)
//
#include <hip/hip_runtime.h>

typedef __bf16 bf16x8 __attribute__((ext_vector_type(8)));
typedef float f32x4 __attribute__((ext_vector_type(4)));
typedef unsigned short u16x8 __attribute__((ext_vector_type(8)));
typedef unsigned short u16x4 __attribute__((ext_vector_type(4)));

__device__ inline unsigned short f2bf(float f) {
    return __builtin_bit_cast(unsigned short, (__bf16)f);
}
__device__ inline float bf2f(unsigned short u) {
    return (float)__builtin_bit_cast(__bf16, u);
}

__device__ inline void storeC(float v, float* p) { *p = v; }
__device__ inline void storeC(float v, unsigned short* p) { *p = f2bf(v); }

#define MFMA16(a, b, c) __builtin_amdgcn_mfma_f32_16x16x32_bf16( \
    __builtin_bit_cast(bf16x8, a), __builtin_bit_cast(bf16x8, b), (c), 0, 0, 0)

// ---------------------------------------------------------------------------
// GEMM: C[M,N] = A[M,K](f32, row-major) * B[K,N](f32, row-major), C in CT
// 128x128 tile, BK=32, 4 waves (2x2 of 64x64), bf16 MFMA 16x16x32.
// B is transposed into LDS [n][k] during staging so fragments are k-contiguous.
// ---------------------------------------------------------------------------
template <typename CT>
__global__ __launch_bounds__(256) void gemm_f32_bf16(
    const float* __restrict__ A, const float* __restrict__ B, CT* __restrict__ C,
    int M, int N, int K)
{
    constexpr int BM = 128, BN = 128, BK = 32, LDT = BK + 8; // 40 elems, 80B row
    __shared__ __attribute__((aligned(16))) unsigned short a_lds[BM * LDT];
    __shared__ __attribute__((aligned(16))) unsigned short b_lds[BN * LDT];

    const int bm0 = blockIdx.y * BM, bn0 = blockIdx.x * BN;
    const int tid = threadIdx.x;
    const int lane = tid & 63, wid = tid >> 6;
    const int wm = (wid >> 1) * 64, wn = (wid & 1) * 64;
    const int l15 = lane & 15, koff = (lane >> 4) * 8;

    f32x4 acc[4][4] = {};

    const int ar = tid >> 3;          // 0..31 (A row within pass)
    const int ac = (tid & 7) * 4;     // 0,4,...,28 (A col)
    const int bn = tid & 127;         // 0..127 (B col)
    const int bk0 = (tid >> 7) * 16;  // 0 or 16 (B k-base)

    for (int kt = 0; kt < K; kt += BK) {
        // ---- stage A tile [128][32] fp32 -> bf16 LDS [m][k]
        #pragma unroll
        for (int p = 0; p < 4; ++p) {
            int r = ar + p * 32;
            float4 v = *(const float4*)&A[(size_t)(bm0 + r) * K + kt + ac];
            u16x4 hv;
            hv[0] = f2bf(v.x); hv[1] = f2bf(v.y); hv[2] = f2bf(v.z); hv[3] = f2bf(v.w);
            *(u16x4*)&a_lds[r * LDT + ac] = hv;
        }
        // ---- stage B tile [32][128] fp32 -> bf16 LDS transposed [n][k]
        {
            const float* bp = &B[(size_t)(kt + bk0) * N + bn0 + bn];
            u16x8 t0, t1;
            #pragma unroll
            for (int j = 0; j < 8; ++j) t0[j] = f2bf(bp[(size_t)j * N]);
            #pragma unroll
            for (int j = 0; j < 8; ++j) t1[j] = f2bf(bp[(size_t)(j + 8) * N]);
            *(u16x8*)&b_lds[bn * LDT + bk0] = t0;
            *(u16x8*)&b_lds[bn * LDT + bk0 + 8] = t1;
        }
        __syncthreads();

        u16x8 af[4], bfr[4];
        #pragma unroll
        for (int i = 0; i < 4; ++i)
            af[i] = *(u16x8*)&a_lds[(wm + i * 16 + l15) * LDT + koff];
        #pragma unroll
        for (int i = 0; i < 4; ++i)
            bfr[i] = *(u16x8*)&b_lds[(wn + i * 16 + l15) * LDT + koff];

        #pragma unroll
        for (int i = 0; i < 4; ++i)
            #pragma unroll
            for (int j = 0; j < 4; ++j)
                acc[i][j] = MFMA16(af[i], bfr[j], acc[i][j]);
        __syncthreads();
    }

    // ---- epilogue: D row = (lane>>4)*4 + reg, col = lane&15
    #pragma unroll
    for (int i = 0; i < 4; ++i)
        #pragma unroll
        for (int r = 0; r < 4; ++r) {
            int row = bm0 + wm + i * 16 + (lane >> 4) * 4 + r;
            size_t base = (size_t)row * N + bn0 + wn + l15;
            #pragma unroll
            for (int j = 0; j < 4; ++j)
                storeC(acc[i][j][r], &C[base + j * 16]);
        }
}

// ---------------------------------------------------------------------------
// Fused RoPE + RMSNorm, in-place on bf16 [S][H*128].
// 8 threads per head; thread handles dims d=t8*8..t8*8+7 and d+64 (rope pairs).
// outscale folds 1/sqrt(HEAD_DIM) into Q.
// ---------------------------------------------------------------------------
__global__ void rope_rmsnorm(unsigned short* __restrict__ X,
                             const int* __restrict__ pos_ids,
                             const float* __restrict__ W, int H, float outscale)
{
    const int s = blockIdx.x;
    const int tid = threadIdx.x;          // H*8 threads
    const int h = tid >> 3, t8 = tid & 7;
    const int rowstride = H * 128;
    unsigned short* p = X + (size_t)s * rowstride + h * 128 + t8 * 8;
    u16x8 lo = *(u16x8*)p;
    u16x8 hi = *(u16x8*)(p + 64);
    const float fpos = (float)pos_ids[s];
    float na[8], nb[8];
    float ss = 0.f;
    #pragma unroll
    for (int j = 0; j < 8; ++j) {
        const int d = t8 * 8 + j;
        float inv = expf(-0.14391156831212787f * (float)d); // ln(10000)/64
        float fr = fpos * inv;
        float c = cosf(fr), sn = sinf(fr);
        float a = bf2f(lo[j]), b = bf2f(hi[j]);
        na[j] = a * c - b * sn;
        nb[j] = b * c + a * sn;
        ss += na[j] * na[j] + nb[j] * nb[j];
    }
    ss += __shfl_xor(ss, 1, 8);
    ss += __shfl_xor(ss, 2, 8);
    ss += __shfl_xor(ss, 4, 8);
    const float rn = rsqrtf(ss * (1.0f / 128.0f) + 1e-6f) * outscale;
    #pragma unroll
    for (int j = 0; j < 8; ++j) {
        const int d = t8 * 8 + j;
        lo[j] = f2bf(na[j] * rn * W[d]);
        hi[j] = f2bf(nb[j] * rn * W[d + 64]);
    }
    *(u16x8*)p = lo;
    *(u16x8*)(p + 64) = hi;
}

// ---------------------------------------------------------------------------
// Causal flash attention. Block = (head, 64 q-rows), 4 waves x 16 rows.
// KV chunks of 32. Q/K staged [row][dim] in LDS, V staged transposed [dim][key].
// P routed through per-wave LDS. GQA: kv head = h/4. Scale pre-folded into Q.
// ---------------------------------------------------------------------------
__global__ __launch_bounds__(256) void attn_kernel(
    const unsigned short* __restrict__ Q, const unsigned short* __restrict__ K,
    const unsigned short* __restrict__ V, float* __restrict__ O)
{
    constexpr int QB = 64, KB = 32, LDQ = 136, LDV = 40;
    __shared__ __attribute__((aligned(16))) unsigned short q_lds[QB * LDQ];
    __shared__ __attribute__((aligned(16))) unsigned short k_lds[KB * LDQ];
    __shared__ __attribute__((aligned(16))) unsigned short v_lds[128 * LDV];
    __shared__ __attribute__((aligned(16))) unsigned short p_lds[4 * 16 * LDV];

    const int h = blockIdx.x;      // 0..31
    const int qb = blockIdx.y;     // 0..31
    const int q0 = qb * QB;
    const int kvh = h >> 2;
    const int tid = threadIdx.x, lane = tid & 63, wid = tid >> 6;
    const int l15 = lane & 15, koff = (lane >> 4) * 8;
    const int qw = q0 + wid * 16;

    // stage Q tile [64][128]
    {
        int qr = tid >> 2;              // 0..63
        int qc = (tid & 3) * 32;        // 0,32,64,96
        const unsigned short* qp = &Q[(size_t)(q0 + qr) * 4096 + h * 128 + qc];
        #pragma unroll
        for (int j = 0; j < 4; ++j)
            *(u16x8*)&q_lds[qr * LDQ + qc + j * 8] = *(const u16x8*)(qp + j * 8);
    }

    f32x4 o_acc[8] = {};
    float m_r[4], l_r[4];
    #pragma unroll
    for (int r = 0; r < 4; ++r) { m_r[r] = -1e30f; l_r[r] = 0.f; }

    const int nchunk = (q0 + QB) / KB;
    for (int ch = 0; ch < nchunk; ++ch) {
        const int kv0 = ch * KB;
        // stage K chunk [32][128]
        {
            int kr = tid >> 3;           // 0..31
            int kd = (tid & 7) * 16;     // 0..112
            const unsigned short* kp = &K[(size_t)(kv0 + kr) * 1024 + kvh * 128 + kd];
            *(u16x8*)&k_lds[kr * LDQ + kd] = *(const u16x8*)kp;
            *(u16x8*)&k_lds[kr * LDQ + kd + 8] = *(const u16x8*)(kp + 8);
        }
        // stage V chunk transposed [128][32]
        {
            int dd = tid & 127, kk0 = (tid >> 7) * 16;
            const unsigned short* vp = &V[(size_t)(kv0 + kk0) * 1024 + kvh * 128 + dd];
            u16x8 t0, t1;
            #pragma unroll
            for (int j = 0; j < 8; ++j) t0[j] = vp[(size_t)j * 1024];
            #pragma unroll
            for (int j = 0; j < 8; ++j) t1[j] = vp[(size_t)(j + 8) * 1024];
            *(u16x8*)&v_lds[dd * LDV + kk0] = t0;
            *(u16x8*)&v_lds[dd * LDV + kk0 + 8] = t1;
        }
        __syncthreads();

        const bool active = (kv0 <= qw + 15);
        if (active) {
            // QK^T: S[16 q][32 keys]
            u16x8 qf[4];
            #pragma unroll
            for (int kk = 0; kk < 4; ++kk)
                qf[kk] = *(u16x8*)&q_lds[(wid * 16 + l15) * LDQ + kk * 32 + koff];
            f32x4 sacc[2] = {};
            #pragma unroll
            for (int jt = 0; jt < 2; ++jt)
                #pragma unroll
                for (int kk = 0; kk < 4; ++kk) {
                    u16x8 kf = *(u16x8*)&k_lds[(jt * 16 + l15) * LDQ + kk * 32 + koff];
                    sacc[jt] = MFMA16(qf[kk], kf, sacc[jt]);
                }
            // causal mask
            #pragma unroll
            for (int jt = 0; jt < 2; ++jt)
                #pragma unroll
                for (int r = 0; r < 4; ++r) {
                    int cg = kv0 + jt * 16 + l15;
                    int rg = qw + (lane >> 4) * 4 + r;
                    if (cg > rg) sacc[jt][r] = -1e9f;
                }
            // online softmax
            float alpha[4];
            #pragma unroll
            for (int r = 0; r < 4; ++r) {
                float mx = fmaxf(sacc[0][r], sacc[1][r]);
                mx = fmaxf(mx, __shfl_xor(mx, 1, 16));
                mx = fmaxf(mx, __shfl_xor(mx, 2, 16));
                mx = fmaxf(mx, __shfl_xor(mx, 4, 16));
                mx = fmaxf(mx, __shfl_xor(mx, 8, 16));
                float mnew = fmaxf(m_r[r], mx);
                alpha[r] = __expf(m_r[r] - mnew);
                m_r[r] = mnew;
            }
            #pragma unroll
            for (int jt = 0; jt < 2; ++jt)
                #pragma unroll
                for (int r = 0; r < 4; ++r)
                    sacc[jt][r] = __expf(sacc[jt][r] - m_r[r]);
            #pragma unroll
            for (int r = 0; r < 4; ++r) {
                float ps = sacc[0][r] + sacc[1][r];
                ps += __shfl_xor(ps, 1, 16);
                ps += __shfl_xor(ps, 2, 16);
                ps += __shfl_xor(ps, 4, 16);
                ps += __shfl_xor(ps, 8, 16);
                l_r[r] = l_r[r] * alpha[r] + ps;
            }
            #pragma unroll
            for (int nt = 0; nt < 8; ++nt)
                #pragma unroll
                for (int r = 0; r < 4; ++r) o_acc[nt][r] *= alpha[r];
            // write P (bf16) to per-wave LDS
            int pb = wid * 16 * LDV;
            #pragma unroll
            for (int jt = 0; jt < 2; ++jt)
                #pragma unroll
                for (int r = 0; r < 4; ++r)
                    p_lds[pb + ((lane >> 4) * 4 + r) * LDV + jt * 16 + l15] =
                        f2bf(sacc[jt][r]);
        }
        __syncthreads();
        if (active) {
            // PV: O[16 q][128 d] += P[16][32] * V[32][128]
            int pb = wid * 16 * LDV;
            u16x8 pf = *(u16x8*)&p_lds[pb + l15 * LDV + koff];
            #pragma unroll
            for (int nt = 0; nt < 8; ++nt) {
                u16x8 vf = *(u16x8*)&v_lds[(nt * 16 + l15) * LDV + koff];
                o_acc[nt] = MFMA16(pf, vf, o_acc[nt]);
            }
        }
        __syncthreads();
    }

    // epilogue: normalize and store fp32 [s][h*128+d]
    float inv_l[4];
    #pragma unroll
    for (int r = 0; r < 4; ++r) inv_l[r] = 1.0f / l_r[r];
    #pragma unroll
    for (int nt = 0; nt < 8; ++nt)
        #pragma unroll
        for (int r = 0; r < 4; ++r) {
            int row = qw + (lane >> 4) * 4 + r;
            int col = h * 128 + nt * 16 + l15;
            O[(size_t)row * 4096 + col] = o_acc[nt][r] * inv_l[r];
        }
}

// ---------------------------------------------------------------------------
extern "C" void kernel_launch(void* const* d_in, const int* in_sizes, int n_in,
                              void* d_out, int out_size, void* d_ws, size_t ws_size,
                              hipStream_t stream)
{
    (void)in_sizes; (void)n_in; (void)out_size; (void)ws_size;
    const float* hidden = (const float*)d_in[0];
    const float* wq     = (const float*)d_in[1];
    const float* wk     = (const float*)d_in[2];
    const float* wv     = (const float*)d_in[3];
    const float* wo     = (const float*)d_in[4];
    const float* qnw    = (const float*)d_in[5];
    const float* knw    = (const float*)d_in[6];
    const int*   pos    = (const int*)d_in[8];
    float* out = (float*)d_out;

    char* ws = (char*)d_ws;
    unsigned short* q_ws = (unsigned short*)(ws);                        // 2048*4096 bf16
    unsigned short* k_ws = (unsigned short*)(ws + (size_t)16777216);     // 2048*1024 bf16
    unsigned short* v_ws = (unsigned short*)(ws + (size_t)20971520);     // 2048*1024 bf16
    float*          a_ws = (float*)(ws + (size_t)25165824);              // 2048*4096 f32

    gemm_f32_bf16<unsigned short><<<dim3(32, 16), 256, 0, stream>>>(
        hidden, wq, q_ws, 2048, 4096, 4096);
    gemm_f32_bf16<unsigned short><<<dim3(8, 16), 256, 0, stream>>>(
        hidden, wk, k_ws, 2048, 1024, 4096);
    gemm_f32_bf16<unsigned short><<<dim3(8, 16), 256, 0, stream>>>(
        hidden, wv, v_ws, 2048, 1024, 4096);
    rope_rmsnorm<<<2048, 256, 0, stream>>>(q_ws, pos, qnw, 32, 0.08838834764831845f);
    rope_rmsnorm<<<2048, 64, 0, stream>>>(k_ws, pos, knw, 8, 1.0f);
    attn_kernel<<<dim3(32, 32), 256, 0, stream>>>(q_ws, k_ws, v_ws, a_ws);
    gemm_f32_bf16<float><<<dim3(32, 16), 256, 0, stream>>>(
        a_ws, wo, out, 2048, 4096, 4096);
}

// Round 2
// 795.400 us; speedup vs baseline: 1.0649x; 1.0649x over previous
//
#include <hip/hip_runtime.h>

typedef __bf16 bf16x8 __attribute__((ext_vector_type(8)));
typedef float f32x4 __attribute__((ext_vector_type(4)));
typedef unsigned short u16x8 __attribute__((ext_vector_type(8)));
typedef unsigned short u16x4 __attribute__((ext_vector_type(4)));

__device__ inline unsigned short f2bf(float f) {
    return __builtin_bit_cast(unsigned short, (__bf16)f);
}
__device__ inline float bf2f(unsigned short u) {
    return (float)__builtin_bit_cast(__bf16, u);
}

__device__ inline void storeC(float v, float* p) { *p = v; }
__device__ inline void storeC(float v, unsigned short* p) { *p = f2bf(v); }

#define MFMA16(a, b, c) __builtin_amdgcn_mfma_f32_16x16x32_bf16( \
    __builtin_bit_cast(bf16x8, a), __builtin_bit_cast(bf16x8, b), (c), 0, 0, 0)

// ---------------------------------------------------------------------------
// GEMM: C[M,N] = A[M,K](f32) * B[K,N](f32). If TC, store C transposed [N][M].
// 128x128 tile, BK=32, 4 waves (2x2 of 64x64), bf16 MFMA 16x16x32.
// ---------------------------------------------------------------------------
template <typename CT, bool TC>
__global__ __launch_bounds__(256) void gemm_f32_bf16(
    const float* __restrict__ A, const float* __restrict__ B, CT* __restrict__ C,
    int M, int N, int K)
{
    constexpr int BM = 128, BN = 128, BK = 32, LDT = BK + 8;
    __shared__ __attribute__((aligned(16))) unsigned short a_lds[BM * LDT];
    __shared__ __attribute__((aligned(16))) unsigned short b_lds[BN * LDT];

    const int bm0 = blockIdx.y * BM, bn0 = blockIdx.x * BN;
    const int tid = threadIdx.x;
    const int lane = tid & 63, wid = tid >> 6;
    const int wm = (wid >> 1) * 64, wn = (wid & 1) * 64;
    const int l15 = lane & 15, koff = (lane >> 4) * 8;

    f32x4 acc[4][4] = {};

    const int ar = tid >> 3;
    const int ac = (tid & 7) * 4;
    const int bn = tid & 127;
    const int bk0 = (tid >> 7) * 16;

    for (int kt = 0; kt < K; kt += BK) {
        #pragma unroll
        for (int p = 0; p < 4; ++p) {
            int r = ar + p * 32;
            float4 v = *(const float4*)&A[(size_t)(bm0 + r) * K + kt + ac];
            u16x4 hv;
            hv[0] = f2bf(v.x); hv[1] = f2bf(v.y); hv[2] = f2bf(v.z); hv[3] = f2bf(v.w);
            *(u16x4*)&a_lds[r * LDT + ac] = hv;
        }
        {
            const float* bp = &B[(size_t)(kt + bk0) * N + bn0 + bn];
            u16x8 t0, t1;
            #pragma unroll
            for (int j = 0; j < 8; ++j) t0[j] = f2bf(bp[(size_t)j * N]);
            #pragma unroll
            for (int j = 0; j < 8; ++j) t1[j] = f2bf(bp[(size_t)(j + 8) * N]);
            *(u16x8*)&b_lds[bn * LDT + bk0] = t0;
            *(u16x8*)&b_lds[bn * LDT + bk0 + 8] = t1;
        }
        __syncthreads();

        u16x8 af[4], bfr[4];
        #pragma unroll
        for (int i = 0; i < 4; ++i)
            af[i] = *(u16x8*)&a_lds[(wm + i * 16 + l15) * LDT + koff];
        #pragma unroll
        for (int i = 0; i < 4; ++i)
            bfr[i] = *(u16x8*)&b_lds[(wn + i * 16 + l15) * LDT + koff];

        #pragma unroll
        for (int i = 0; i < 4; ++i)
            #pragma unroll
            for (int j = 0; j < 4; ++j)
                acc[i][j] = MFMA16(af[i], bfr[j], acc[i][j]);
        __syncthreads();
    }

    #pragma unroll
    for (int i = 0; i < 4; ++i)
        #pragma unroll
        for (int r = 0; r < 4; ++r) {
            int row = bm0 + wm + i * 16 + (lane >> 4) * 4 + r;
            if constexpr (TC) {
                #pragma unroll
                for (int j = 0; j < 4; ++j)
                    storeC(acc[i][j][r], &C[(size_t)(bn0 + wn + l15 + j * 16) * M + row]);
            } else {
                size_t base = (size_t)row * N + bn0 + wn + l15;
                #pragma unroll
                for (int j = 0; j < 4; ++j)
                    storeC(acc[i][j][r], &C[base + j * 16]);
            }
        }
}

// ---------------------------------------------------------------------------
// Fused RoPE + RMSNorm, in-place on bf16 [S][H*128].
// ---------------------------------------------------------------------------
__global__ void rope_rmsnorm(unsigned short* __restrict__ X,
                             const int* __restrict__ pos_ids,
                             const float* __restrict__ W, int H, float outscale)
{
    const int s = blockIdx.x;
    const int tid = threadIdx.x;
    const int h = tid >> 3, t8 = tid & 7;
    const int rowstride = H * 128;
    unsigned short* p = X + (size_t)s * rowstride + h * 128 + t8 * 8;
    u16x8 lo = *(u16x8*)p;
    u16x8 hi = *(u16x8*)(p + 64);
    const float fpos = (float)pos_ids[s];
    float na[8], nb[8];
    float ss = 0.f;
    #pragma unroll
    for (int j = 0; j < 8; ++j) {
        const int d = t8 * 8 + j;
        float inv = expf(-0.14391156831212787f * (float)d);
        float fr = fpos * inv;
        float c = cosf(fr), sn = sinf(fr);
        float a = bf2f(lo[j]), b = bf2f(hi[j]);
        na[j] = a * c - b * sn;
        nb[j] = b * c + a * sn;
        ss += na[j] * na[j] + nb[j] * nb[j];
    }
    ss += __shfl_xor(ss, 1, 8);
    ss += __shfl_xor(ss, 2, 8);
    ss += __shfl_xor(ss, 4, 8);
    const float rn = rsqrtf(ss * (1.0f / 128.0f) + 1e-6f) * outscale;
    #pragma unroll
    for (int j = 0; j < 8; ++j) {
        const int d = t8 * 8 + j;
        lo[j] = f2bf(na[j] * rn * W[d]);
        hi[j] = f2bf(nb[j] * rn * W[d + 64]);
    }
    *(u16x8*)p = lo;
    *(u16x8*)(p + 64) = hi;
}

// ---------------------------------------------------------------------------
// Causal flash attention, V^T input.
// Block = 4 waves x 32 q-rows = 128 q-rows per head. KV chunks of 64.
// Q hoisted to registers. K staged [key][d], V^T staged [d][key] (both
// coalesced global + linear LDS writes). P routed via per-wave LDS.
// Async-stage split: next chunk's global loads issued before compute.
// ---------------------------------------------------------------------------
__global__ __launch_bounds__(256, 2) void attn_kernel(
    const unsigned short* __restrict__ Q, const unsigned short* __restrict__ K,
    const unsigned short* __restrict__ VT, float* __restrict__ O)
{
    constexpr int LDK = 136, LDV = 72, LDP = 72;
    __shared__ __attribute__((aligned(16))) unsigned short k_lds[64 * LDK];
    __shared__ __attribute__((aligned(16))) unsigned short v_lds[128 * LDV];
    __shared__ __attribute__((aligned(16))) unsigned short p_lds[4 * 2 * 16 * LDP];

    const int bid = blockIdx.x;
    const int h = bid & 31;
    const int qp = bid >> 5;
    const int qb = qp < 8 ? qp : 23 - qp;   // pair heavy+light blocks per CU
    const int q0 = qb * 128;
    const int kvh = h >> 2;
    const int tid = threadIdx.x, lane = tid & 63, wid = tid >> 6;
    const int l15 = lane & 15, koff = (lane >> 4) * 8;
    const int qw = q0 + wid * 32;

    // hoist Q fragments to registers
    u16x8 qf[2][4];
    #pragma unroll
    for (int qt = 0; qt < 2; ++qt)
        #pragma unroll
        for (int kk = 0; kk < 4; ++kk)
            qf[qt][kk] = *(const u16x8*)&Q[(size_t)(qw + qt * 16 + l15) * 4096 +
                                           h * 128 + kk * 32 + koff];

    f32x4 o_acc[2][8] = {};
    float m_r[2][4], l_r[2][4];
    #pragma unroll
    for (int qt = 0; qt < 2; ++qt)
        #pragma unroll
        for (int r = 0; r < 4; ++r) { m_r[qt][r] = -1e30f; l_r[qt][r] = 0.f; }

    // staging mapping
    const int kr = tid >> 2, kd = (tid & 3) * 32;       // K: 64 rows, 64B/thread
    const int vr = tid >> 1, vc = (tid & 1) * 32;       // VT: 128 rows, 64B/thread
    const unsigned short* kg = K + (size_t)kvh * 128 + kd;
    const unsigned short* vg = VT + (size_t)(kvh * 128 + vr) * 2048 + vc;

    const int nchunk = qb * 2 + 2;
    u16x8 kst[4], vst[4];
    #pragma unroll
    for (int j = 0; j < 4; ++j) {
        kst[j] = *(const u16x8*)&kg[(size_t)kr * 1024 + j * 8];
        vst[j] = *(const u16x8*)&vg[j * 8];
    }

    for (int ch = 0; ch < nchunk; ++ch) {
        const int kv0 = ch * 64;
        __syncthreads();   // previous chunk's LDS reads complete
        #pragma unroll
        for (int j = 0; j < 4; ++j) {
            *(u16x8*)&k_lds[kr * LDK + kd + j * 8] = kst[j];
            *(u16x8*)&v_lds[vr * LDV + vc + j * 8] = vst[j];
        }
        __syncthreads();   // staged data visible
        if (ch + 1 < nchunk) {
            const int kv1 = kv0 + 64;
            #pragma unroll
            for (int j = 0; j < 4; ++j) {
                kst[j] = *(const u16x8*)&kg[(size_t)(kv1 + kr) * 1024 + j * 8];
                vst[j] = *(const u16x8*)&vg[kv1 + j * 8];
            }
        }

        if (kv0 <= qw + 31) {
            // ---- QK^T: S[32 q][64 keys]
            f32x4 sacc[2][4] = {};
            #pragma unroll
            for (int kk = 0; kk < 4; ++kk)
                #pragma unroll
                for (int jt = 0; jt < 4; ++jt) {
                    u16x8 kf = *(u16x8*)&k_lds[(jt * 16 + l15) * LDK + kk * 32 + koff];
                    #pragma unroll
                    for (int qt = 0; qt < 2; ++qt)
                        sacc[qt][jt] = MFMA16(qf[qt][kk], kf, sacc[qt][jt]);
                }

            #pragma unroll
            for (int qt = 0; qt < 2; ++qt) {
                const int rbase = qw + qt * 16 + (lane >> 4) * 4;
                // causal mask
                #pragma unroll
                for (int jt = 0; jt < 4; ++jt)
                    #pragma unroll
                    for (int r = 0; r < 4; ++r)
                        if (kv0 + jt * 16 + l15 > rbase + r) sacc[qt][jt][r] = -1e9f;
                // online softmax
                float alpha[4];
                #pragma unroll
                for (int r = 0; r < 4; ++r) {
                    float mx = fmaxf(fmaxf(sacc[0 + 0][0][r], sacc[qt][1][r]),
                                     fmaxf(sacc[qt][2][r], sacc[qt][3][r]));
                    mx = fmaxf(sacc[qt][0][r], mx);
                    mx = fmaxf(mx, __shfl_xor(mx, 1, 16));
                    mx = fmaxf(mx, __shfl_xor(mx, 2, 16));
                    mx = fmaxf(mx, __shfl_xor(mx, 4, 16));
                    mx = fmaxf(mx, __shfl_xor(mx, 8, 16));
                    float mnew = fmaxf(m_r[qt][r], mx);
                    alpha[r] = __expf(m_r[qt][r] - mnew);
                    m_r[qt][r] = mnew;
                }
                #pragma unroll
                for (int jt = 0; jt < 4; ++jt)
                    #pragma unroll
                    for (int r = 0; r < 4; ++r)
                        sacc[qt][jt][r] = __expf(sacc[qt][jt][r] - m_r[qt][r]);
                #pragma unroll
                for (int r = 0; r < 4; ++r) {
                    float ps = (sacc[qt][0][r] + sacc[qt][1][r]) +
                               (sacc[qt][2][r] + sacc[qt][3][r]);
                    ps += __shfl_xor(ps, 1, 16);
                    ps += __shfl_xor(ps, 2, 16);
                    ps += __shfl_xor(ps, 4, 16);
                    ps += __shfl_xor(ps, 8, 16);
                    l_r[qt][r] = l_r[qt][r] * alpha[r] + ps;
                }
                #pragma unroll
                for (int nt = 0; nt < 8; ++nt)
                    #pragma unroll
                    for (int r = 0; r < 4; ++r) o_acc[qt][nt][r] *= alpha[r];
                // write P to per-wave LDS
                const int pb = ((wid * 2 + qt) * 16) * LDP;
                #pragma unroll
                for (int jt = 0; jt < 4; ++jt)
                    #pragma unroll
                    for (int r = 0; r < 4; ++r)
                        p_lds[pb + ((lane >> 4) * 4 + r) * LDP + jt * 16 + l15] =
                            f2bf(sacc[qt][jt][r]);
            }

            // ---- PV: O[32 q][128 d] += P[32][64] * V[64][128]
            u16x8 pf[2][2];
            #pragma unroll
            for (int qt = 0; qt < 2; ++qt)
                #pragma unroll
                for (int ks = 0; ks < 2; ++ks)
                    pf[qt][ks] = *(u16x8*)&p_lds[((wid * 2 + qt) * 16 + l15) * LDP +
                                                 ks * 32 + koff];
            #pragma unroll
            for (int nt = 0; nt < 8; ++nt)
                #pragma unroll
                for (int ks = 0; ks < 2; ++ks) {
                    u16x8 vf = *(u16x8*)&v_lds[(nt * 16 + l15) * LDV + ks * 32 + koff];
                    #pragma unroll
                    for (int qt = 0; qt < 2; ++qt)
                        o_acc[qt][nt] = MFMA16(pf[qt][ks], vf, o_acc[qt][nt]);
                }
        }
    }

    // epilogue
    #pragma unroll
    for (int qt = 0; qt < 2; ++qt)
        #pragma unroll
        for (int r = 0; r < 4; ++r) {
            float inv_l = 1.0f / l_r[qt][r];
            int row = qw + qt * 16 + (lane >> 4) * 4 + r;
            #pragma unroll
            for (int nt = 0; nt < 8; ++nt)
                O[(size_t)row * 4096 + h * 128 + nt * 16 + l15] =
                    o_acc[qt][nt][r] * inv_l;
        }
}

// ---------------------------------------------------------------------------
extern "C" void kernel_launch(void* const* d_in, const int* in_sizes, int n_in,
                              void* d_out, int out_size, void* d_ws, size_t ws_size,
                              hipStream_t stream)
{
    (void)in_sizes; (void)n_in; (void)out_size; (void)ws_size;
    const float* hidden = (const float*)d_in[0];
    const float* wq     = (const float*)d_in[1];
    const float* wk     = (const float*)d_in[2];
    const float* wv     = (const float*)d_in[3];
    const float* wo     = (const float*)d_in[4];
    const float* qnw    = (const float*)d_in[5];
    const float* knw    = (const float*)d_in[6];
    const int*   pos    = (const int*)d_in[8];
    float* out = (float*)d_out;

    char* ws = (char*)d_ws;
    unsigned short* q_ws  = (unsigned short*)(ws);                      // 2048x4096 bf16
    unsigned short* k_ws  = (unsigned short*)(ws + (size_t)16777216);   // 2048x1024 bf16
    unsigned short* vt_ws = (unsigned short*)(ws + (size_t)20971520);   // 1024x2048 bf16 (V^T)
    float*          a_ws  = (float*)(ws + (size_t)25165824);            // 2048x4096 f32

    gemm_f32_bf16<unsigned short, false><<<dim3(32, 16), 256, 0, stream>>>(
        hidden, wq, q_ws, 2048, 4096, 4096);
    gemm_f32_bf16<unsigned short, false><<<dim3(8, 16), 256, 0, stream>>>(
        hidden, wk, k_ws, 2048, 1024, 4096);
    gemm_f32_bf16<unsigned short, true><<<dim3(8, 16), 256, 0, stream>>>(
        hidden, wv, vt_ws, 2048, 1024, 4096);
    rope_rmsnorm<<<2048, 256, 0, stream>>>(q_ws, pos, qnw, 32, 0.08838834764831845f);
    rope_rmsnorm<<<2048, 64, 0, stream>>>(k_ws, pos, knw, 8, 1.0f);
    attn_kernel<<<512, 256, 0, stream>>>(q_ws, k_ws, vt_ws, a_ws);
    gemm_f32_bf16<float, false><<<dim3(32, 16), 256, 0, stream>>>(
        a_ws, wo, out, 2048, 4096, 4096);
}

// Round 3
// 539.789 us; speedup vs baseline: 1.5692x; 1.4735x over previous
//
#include <hip/hip_runtime.h>

typedef __bf16 bf16x8 __attribute__((ext_vector_type(8)));
typedef float f32x4 __attribute__((ext_vector_type(4)));
typedef unsigned short u16x8 __attribute__((ext_vector_type(8)));
typedef unsigned short u16x4 __attribute__((ext_vector_type(4)));
typedef unsigned short u16x2 __attribute__((ext_vector_type(2)));

__device__ inline unsigned short f2bf(float f) {
    return __builtin_bit_cast(unsigned short, (__bf16)f);
}
__device__ inline float bf2f(unsigned short u) {
    return (float)__builtin_bit_cast(__bf16, u);
}

__device__ inline void storeC(float v, float* p) { *p = v; }
__device__ inline void storeC(float v, unsigned short* p) { *p = f2bf(v); }

#define MFMA16(a, b, c) __builtin_amdgcn_mfma_f32_16x16x32_bf16( \
    __builtin_bit_cast(bf16x8, a), __builtin_bit_cast(bf16x8, b), (c), 0, 0, 0)

// async global->LDS, 16B per lane; LDS dest = wave-uniform base + lane*16
__device__ inline void gload16(const unsigned short* g, unsigned short* l) {
    __builtin_amdgcn_global_load_lds(
        (const __attribute__((address_space(1))) unsigned int*)(g),
        (__attribute__((address_space(3))) unsigned int*)(l), 16, 0, 0);
}

// ---------------------------------------------------------------------------
// convert f32 -> bf16 elementwise. n must be multiple of 8*256.
// ---------------------------------------------------------------------------
__global__ __launch_bounds__(256) void convert_f32_bf16(
    const float* __restrict__ X, unsigned short* __restrict__ Y)
{
    const size_t i = ((size_t)blockIdx.x * 256 + threadIdx.x) * 8;
    float4 v0 = *(const float4*)&X[i];
    float4 v1 = *(const float4*)&X[i + 4];
    u16x8 o;
    o[0] = f2bf(v0.x); o[1] = f2bf(v0.y); o[2] = f2bf(v0.z); o[3] = f2bf(v0.w);
    o[4] = f2bf(v1.x); o[5] = f2bf(v1.y); o[6] = f2bf(v1.z); o[7] = f2bf(v1.w);
    *(u16x8*)&Y[i] = o;
}

// ---------------------------------------------------------------------------
// transpose + convert: W f32 [K][N] -> WT bf16 [N][K]. 64x64 tiles.
// ---------------------------------------------------------------------------
__global__ __launch_bounds__(256) void transpose_f32_bf16(
    const float* __restrict__ W, unsigned short* __restrict__ WT, int K, int N)
{
    constexpr int LDT = 66;
    __shared__ unsigned short t_lds[64 * LDT];
    const int kt = blockIdx.x * 64, nt = blockIdx.y * 64;
    const int tid = threadIdx.x;
    // load [k][n] 64x64 f32, convert, store LDS [k][n]
    const int c = (tid & 15) * 4;
    #pragma unroll
    for (int p = 0; p < 4; ++p) {
        const int r = p * 16 + (tid >> 4);
        float4 v = *(const float4*)&W[(size_t)(kt + r) * N + nt + c];
        u16x2 h0, h1;
        h0[0] = f2bf(v.x); h0[1] = f2bf(v.y);
        h1[0] = f2bf(v.z); h1[1] = f2bf(v.w);
        *(u16x2*)&t_lds[r * LDT + c] = h0;
        *(u16x2*)&t_lds[r * LDT + c + 2] = h1;
    }
    __syncthreads();
    // write rows of WT: row n, 64 k-elems
    const int kc = (tid & 7) * 8;
    #pragma unroll
    for (int p = 0; p < 2; ++p) {
        const int n = p * 32 + (tid >> 3);
        u16x8 o;
        #pragma unroll
        for (int j = 0; j < 8; ++j) o[j] = t_lds[(kc + j) * LDT + n];
        *(u16x8*)&WT[(size_t)(nt + n) * K + kt + kc] = o;
    }
}

// ---------------------------------------------------------------------------
// GEMM (m97 structure): C[M,N] = A[M,K] * B^T  with A,B bf16, B stored [N][K].
// 128x128 tile, BK=64, 4 waves (2x2 of 64x64), global_load_lds staging.
// If TC, C is stored transposed [N][M].
// ---------------------------------------------------------------------------
template <typename CT, bool TC>
__global__ __launch_bounds__(256) void gemm_bf16_bt(
    const unsigned short* __restrict__ A, const unsigned short* __restrict__ B,
    CT* __restrict__ C, int M, int N, int K)
{
    constexpr int BK = 64;
    __shared__ __attribute__((aligned(16))) unsigned short a_lds[128 * BK];
    __shared__ __attribute__((aligned(16))) unsigned short b_lds[128 * BK];

    const int bm0 = blockIdx.y * 128, bn0 = blockIdx.x * 128;
    const int tid = threadIdx.x;
    const int lane = tid & 63, wid = tid >> 6;
    const int wm = (wid >> 1) * 64, wn = (wid & 1) * 64;
    const int l15 = lane & 15, koff = (lane >> 4) * 8;

    f32x4 acc[4][4] = {};

    // staging addresses: pass p covers rows (p*4+wid)*8 .. +7, lane covers
    // row + (lane>>3), halfwords (lane&7)*8 .. +7  (16B per lane, linear LDS)
    const unsigned short* ag[4];
    const unsigned short* bg[4];
    #pragma unroll
    for (int p = 0; p < 4; ++p) {
        const int r = (p * 4 + wid) * 8 + (lane >> 3);
        const int cc = (lane & 7) * 8;
        ag[p] = A + (size_t)(bm0 + r) * K + cc;
        bg[p] = B + (size_t)(bn0 + r) * K + cc;
    }

    for (int kt = 0; kt < K; kt += BK) {
        #pragma unroll
        for (int p = 0; p < 4; ++p) {
            gload16(ag[p] + kt, &a_lds[(p * 4 + wid) * 512]);
            gload16(bg[p] + kt, &b_lds[(p * 4 + wid) * 512]);
        }
        __syncthreads();

        #pragma unroll
        for (int kk = 0; kk < 2; ++kk) {
            u16x8 af[4], bfr[4];
            #pragma unroll
            for (int i = 0; i < 4; ++i)
                af[i] = *(u16x8*)&a_lds[(wm + i * 16 + l15) * BK + kk * 32 + koff];
            #pragma unroll
            for (int j = 0; j < 4; ++j)
                bfr[j] = *(u16x8*)&b_lds[(wn + j * 16 + l15) * BK + kk * 32 + koff];
            #pragma unroll
            for (int i = 0; i < 4; ++i)
                #pragma unroll
                for (int j = 0; j < 4; ++j)
                    acc[i][j] = MFMA16(af[i], bfr[j], acc[i][j]);
        }
        __syncthreads();
    }

    #pragma unroll
    for (int i = 0; i < 4; ++i)
        #pragma unroll
        for (int r = 0; r < 4; ++r) {
            int row = bm0 + wm + i * 16 + (lane >> 4) * 4 + r;
            if constexpr (TC) {
                #pragma unroll
                for (int j = 0; j < 4; ++j)
                    storeC(acc[i][j][r], &C[(size_t)(bn0 + wn + l15 + j * 16) * M + row]);
            } else {
                size_t base = (size_t)row * N + bn0 + wn + l15;
                #pragma unroll
                for (int j = 0; j < 4; ++j)
                    storeC(acc[i][j][r], &C[base + j * 16]);
            }
        }
}

// ---------------------------------------------------------------------------
// Fused RoPE + RMSNorm, in-place on bf16 [S][H*128].
// ---------------------------------------------------------------------------
__global__ void rope_rmsnorm(unsigned short* __restrict__ X,
                             const int* __restrict__ pos_ids,
                             const float* __restrict__ W, int H, float outscale)
{
    const int s = blockIdx.x;
    const int tid = threadIdx.x;
    const int h = tid >> 3, t8 = tid & 7;
    const int rowstride = H * 128;
    unsigned short* p = X + (size_t)s * rowstride + h * 128 + t8 * 8;
    u16x8 lo = *(u16x8*)p;
    u16x8 hi = *(u16x8*)(p + 64);
    const float fpos = (float)pos_ids[s];
    float na[8], nb[8];
    float ss = 0.f;
    #pragma unroll
    for (int j = 0; j < 8; ++j) {
        const int d = t8 * 8 + j;
        float inv = expf(-0.14391156831212787f * (float)d);
        float fr = fpos * inv;
        float c = cosf(fr), sn = sinf(fr);
        float a = bf2f(lo[j]), b = bf2f(hi[j]);
        na[j] = a * c - b * sn;
        nb[j] = b * c + a * sn;
        ss += na[j] * na[j] + nb[j] * nb[j];
    }
    ss += __shfl_xor(ss, 1, 8);
    ss += __shfl_xor(ss, 2, 8);
    ss += __shfl_xor(ss, 4, 8);
    const float rn = rsqrtf(ss * (1.0f / 128.0f) + 1e-6f) * outscale;
    #pragma unroll
    for (int j = 0; j < 8; ++j) {
        const int d = t8 * 8 + j;
        lo[j] = f2bf(na[j] * rn * W[d]);
        hi[j] = f2bf(nb[j] * rn * W[d + 64]);
    }
    *(u16x8*)p = lo;
    *(u16x8*)(p + 64) = hi;
}

// ---------------------------------------------------------------------------
// Causal flash attention, V^T input, bf16 output.
// Block = 4 waves x 32 q-rows = 128 q-rows per head. KV chunks of 64.
// ---------------------------------------------------------------------------
__global__ __launch_bounds__(256, 2) void attn_kernel(
    const unsigned short* __restrict__ Q, const unsigned short* __restrict__ K,
    const unsigned short* __restrict__ VT, unsigned short* __restrict__ O)
{
    constexpr int LDK = 136, LDV = 72, LDP = 72;
    __shared__ __attribute__((aligned(16))) unsigned short k_lds[64 * LDK];
    __shared__ __attribute__((aligned(16))) unsigned short v_lds[128 * LDV];
    __shared__ __attribute__((aligned(16))) unsigned short p_lds[4 * 2 * 16 * LDP];

    const int bid = blockIdx.x;
    const int h = bid & 31;
    const int qp = bid >> 5;
    const int qb = qp < 8 ? qp : 23 - qp;
    const int q0 = qb * 128;
    const int kvh = h >> 2;
    const int tid = threadIdx.x, lane = tid & 63, wid = tid >> 6;
    const int l15 = lane & 15, koff = (lane >> 4) * 8;
    const int qw = q0 + wid * 32;

    u16x8 qf[2][4];
    #pragma unroll
    for (int qt = 0; qt < 2; ++qt)
        #pragma unroll
        for (int kk = 0; kk < 4; ++kk)
            qf[qt][kk] = *(const u16x8*)&Q[(size_t)(qw + qt * 16 + l15) * 4096 +
                                           h * 128 + kk * 32 + koff];

    f32x4 o_acc[2][8] = {};
    float m_r[2][4], l_r[2][4];
    #pragma unroll
    for (int qt = 0; qt < 2; ++qt)
        #pragma unroll
        for (int r = 0; r < 4; ++r) { m_r[qt][r] = -1e30f; l_r[qt][r] = 0.f; }

    const int kr = tid >> 2, kd = (tid & 3) * 32;
    const int vr = tid >> 1, vc = (tid & 1) * 32;
    const unsigned short* kg = K + (size_t)kvh * 128 + kd;
    const unsigned short* vg = VT + (size_t)(kvh * 128 + vr) * 2048 + vc;

    const int nchunk = qb * 2 + 2;
    u16x8 kst[4], vst[4];
    #pragma unroll
    for (int j = 0; j < 4; ++j) {
        kst[j] = *(const u16x8*)&kg[(size_t)kr * 1024 + j * 8];
        vst[j] = *(const u16x8*)&vg[j * 8];
    }

    for (int ch = 0; ch < nchunk; ++ch) {
        const int kv0 = ch * 64;
        __syncthreads();
        #pragma unroll
        for (int j = 0; j < 4; ++j) {
            *(u16x8*)&k_lds[kr * LDK + kd + j * 8] = kst[j];
            *(u16x8*)&v_lds[vr * LDV + vc + j * 8] = vst[j];
        }
        __syncthreads();
        if (ch + 1 < nchunk) {
            const int kv1 = kv0 + 64;
            #pragma unroll
            for (int j = 0; j < 4; ++j) {
                kst[j] = *(const u16x8*)&kg[(size_t)(kv1 + kr) * 1024 + j * 8];
                vst[j] = *(const u16x8*)&vg[kv1 + j * 8];
            }
        }

        if (kv0 <= qw + 31) {
            f32x4 sacc[2][4] = {};
            #pragma unroll
            for (int kk = 0; kk < 4; ++kk)
                #pragma unroll
                for (int jt = 0; jt < 4; ++jt) {
                    u16x8 kf = *(u16x8*)&k_lds[(jt * 16 + l15) * LDK + kk * 32 + koff];
                    #pragma unroll
                    for (int qt = 0; qt < 2; ++qt)
                        sacc[qt][jt] = MFMA16(qf[qt][kk], kf, sacc[qt][jt]);
                }

            #pragma unroll
            for (int qt = 0; qt < 2; ++qt) {
                const int rbase = qw + qt * 16 + (lane >> 4) * 4;
                #pragma unroll
                for (int jt = 0; jt < 4; ++jt)
                    #pragma unroll
                    for (int r = 0; r < 4; ++r)
                        if (kv0 + jt * 16 + l15 > rbase + r) sacc[qt][jt][r] = -1e9f;
                float alpha[4];
                #pragma unroll
                for (int r = 0; r < 4; ++r) {
                    float mx = fmaxf(fmaxf(sacc[qt][0][r], sacc[qt][1][r]),
                                     fmaxf(sacc[qt][2][r], sacc[qt][3][r]));
                    mx = fmaxf(mx, __shfl_xor(mx, 1, 16));
                    mx = fmaxf(mx, __shfl_xor(mx, 2, 16));
                    mx = fmaxf(mx, __shfl_xor(mx, 4, 16));
                    mx = fmaxf(mx, __shfl_xor(mx, 8, 16));
                    float mnew = fmaxf(m_r[qt][r], mx);
                    alpha[r] = __expf(m_r[qt][r] - mnew);
                    m_r[qt][r] = mnew;
                }
                #pragma unroll
                for (int jt = 0; jt < 4; ++jt)
                    #pragma unroll
                    for (int r = 0; r < 4; ++r)
                        sacc[qt][jt][r] = __expf(sacc[qt][jt][r] - m_r[qt][r]);
                #pragma unroll
                for (int r = 0; r < 4; ++r) {
                    float ps = (sacc[qt][0][r] + sacc[qt][1][r]) +
                               (sacc[qt][2][r] + sacc[qt][3][r]);
                    ps += __shfl_xor(ps, 1, 16);
                    ps += __shfl_xor(ps, 2, 16);
                    ps += __shfl_xor(ps, 4, 16);
                    ps += __shfl_xor(ps, 8, 16);
                    l_r[qt][r] = l_r[qt][r] * alpha[r] + ps;
                }
                #pragma unroll
                for (int nt = 0; nt < 8; ++nt)
                    #pragma unroll
                    for (int r = 0; r < 4; ++r) o_acc[qt][nt][r] *= alpha[r];
                const int pb = ((wid * 2 + qt) * 16) * LDP;
                #pragma unroll
                for (int jt = 0; jt < 4; ++jt)
                    #pragma unroll
                    for (int r = 0; r < 4; ++r)
                        p_lds[pb + ((lane >> 4) * 4 + r) * LDP + jt * 16 + l15] =
                            f2bf(sacc[qt][jt][r]);
            }

            u16x8 pf[2][2];
            #pragma unroll
            for (int qt = 0; qt < 2; ++qt)
                #pragma unroll
                for (int ks = 0; ks < 2; ++ks)
                    pf[qt][ks] = *(u16x8*)&p_lds[((wid * 2 + qt) * 16 + l15) * LDP +
                                                 ks * 32 + koff];
            #pragma unroll
            for (int nt = 0; nt < 8; ++nt)
                #pragma unroll
                for (int ks = 0; ks < 2; ++ks) {
                    u16x8 vf = *(u16x8*)&v_lds[(nt * 16 + l15) * LDV + ks * 32 + koff];
                    #pragma unroll
                    for (int qt = 0; qt < 2; ++qt)
                        o_acc[qt][nt] = MFMA16(pf[qt][ks], vf, o_acc[qt][nt]);
                }
        }
    }

    #pragma unroll
    for (int qt = 0; qt < 2; ++qt)
        #pragma unroll
        for (int r = 0; r < 4; ++r) {
            float inv_l = 1.0f / l_r[qt][r];
            int row = qw + qt * 16 + (lane >> 4) * 4 + r;
            #pragma unroll
            for (int nt = 0; nt < 8; ++nt)
                O[(size_t)row * 4096 + h * 128 + nt * 16 + l15] =
                    f2bf(o_acc[qt][nt][r] * inv_l);
        }
}

// ---------------------------------------------------------------------------
extern "C" void kernel_launch(void* const* d_in, const int* in_sizes, int n_in,
                              void* d_out, int out_size, void* d_ws, size_t ws_size,
                              hipStream_t stream)
{
    (void)in_sizes; (void)n_in; (void)out_size; (void)ws_size;
    const float* hidden = (const float*)d_in[0];
    const float* wq     = (const float*)d_in[1];
    const float* wk     = (const float*)d_in[2];
    const float* wv     = (const float*)d_in[3];
    const float* wo     = (const float*)d_in[4];
    const float* qnw    = (const float*)d_in[5];
    const float* knw    = (const float*)d_in[6];
    const int*   pos    = (const int*)d_in[8];
    float* out = (float*)d_out;

    const size_t MB = 1024 * 1024;
    char* ws = (char*)d_ws;
    unsigned short* q_ws  = (unsigned short*)(ws);             // 16 MB  [2048][4096]
    unsigned short* k_ws  = (unsigned short*)(ws + 16 * MB);   //  4 MB  [2048][1024]
    unsigned short* vt_ws = (unsigned short*)(ws + 20 * MB);   //  4 MB  [1024][2048]
    unsigned short* hb    = (unsigned short*)(ws + 24 * MB);   // 16 MB  hidden bf16
    unsigned short* a_ws  = hb;                                // reuse: attn out bf16
    unsigned short* wqt   = (unsigned short*)(ws + 40 * MB);   // 32 MB  [4096][4096]
    unsigned short* wkt   = (unsigned short*)(ws + 72 * MB);   //  8 MB  [1024][4096]
    unsigned short* wvt   = (unsigned short*)(ws + 80 * MB);   //  8 MB  [1024][4096]
    unsigned short* wot   = (unsigned short*)(ws + 88 * MB);   // 32 MB  [4096][4096]

    // prep: bf16 conversion + weight transposes
    convert_f32_bf16<<<4096, 256, 0, stream>>>(hidden, hb);
    transpose_f32_bf16<<<dim3(64, 64), 256, 0, stream>>>(wq, wqt, 4096, 4096);
    transpose_f32_bf16<<<dim3(64, 16), 256, 0, stream>>>(wk, wkt, 4096, 1024);
    transpose_f32_bf16<<<dim3(64, 16), 256, 0, stream>>>(wv, wvt, 4096, 1024);
    transpose_f32_bf16<<<dim3(64, 64), 256, 0, stream>>>(wo, wot, 4096, 4096);

    // projections
    gemm_bf16_bt<unsigned short, false><<<dim3(32, 16), 256, 0, stream>>>(
        hb, wqt, q_ws, 2048, 4096, 4096);
    gemm_bf16_bt<unsigned short, false><<<dim3(8, 16), 256, 0, stream>>>(
        hb, wkt, k_ws, 2048, 1024, 4096);
    gemm_bf16_bt<unsigned short, true><<<dim3(8, 16), 256, 0, stream>>>(
        hb, wvt, vt_ws, 2048, 1024, 4096);

    rope_rmsnorm<<<2048, 256, 0, stream>>>(q_ws, pos, qnw, 32, 0.08838834764831845f);
    rope_rmsnorm<<<2048, 64, 0, stream>>>(k_ws, pos, knw, 8, 1.0f);

    attn_kernel<<<512, 256, 0, stream>>>(q_ws, k_ws, vt_ws, a_ws);

    gemm_bf16_bt<float, false><<<dim3(32, 16), 256, 0, stream>>>(
        a_ws, wot, out, 2048, 4096, 4096);
}

// Round 4
// 457.728 us; speedup vs baseline: 1.8505x; 1.1793x over previous
//
#include <hip/hip_runtime.h>

typedef __bf16 bf16x8 __attribute__((ext_vector_type(8)));
typedef float f32x4 __attribute__((ext_vector_type(4)));
typedef unsigned short u16x8 __attribute__((ext_vector_type(8)));
typedef unsigned short u16x4 __attribute__((ext_vector_type(4)));
typedef unsigned short u16x2 __attribute__((ext_vector_type(2)));

__device__ inline unsigned short f2bf(float f) {
    return __builtin_bit_cast(unsigned short, (__bf16)f);
}
__device__ inline float bf2f(unsigned short u) {
    return (float)__builtin_bit_cast(__bf16, u);
}

__device__ inline void storeC(float v, float* p) { *p = v; }
__device__ inline void storeC(float v, unsigned short* p) { *p = f2bf(v); }

#define MFMA16(a, b, c) __builtin_amdgcn_mfma_f32_16x16x32_bf16( \
    __builtin_bit_cast(bf16x8, a), __builtin_bit_cast(bf16x8, b), (c), 0, 0, 0)

// async global->LDS, 16B per lane; LDS dest = wave-uniform base + lane*16
__device__ inline void gload16(const unsigned short* g, unsigned short* l) {
    __builtin_amdgcn_global_load_lds(
        (const __attribute__((address_space(1))) unsigned int*)(g),
        (__attribute__((address_space(3))) unsigned int*)(l), 16, 0, 0);
}

__device__ __forceinline__ void bar() {
    asm volatile("" ::: "memory");
    __builtin_amdgcn_s_barrier();
    asm volatile("" ::: "memory");
}
#define WAITVM(N) asm volatile("s_waitcnt vmcnt(" #N ")" ::: "memory")

// ---------------------------------------------------------------------------
// convert f32 -> bf16, writing st-swizzled rows (slot ^= row&7 within each
// 64-halfword k-block). Row length hardcoded 4096 (hidden).
// ---------------------------------------------------------------------------
__global__ __launch_bounds__(256) void convert_f32_bf16_swz(
    const float* __restrict__ X, unsigned short* __restrict__ Y)
{
    const size_t i = ((size_t)blockIdx.x * 256 + threadIdx.x) * 8;
    const size_t row7 = (i >> 12) & 7;
    float4 v0 = *(const float4*)&X[i];
    float4 v1 = *(const float4*)&X[i + 4];
    u16x8 o;
    o[0] = f2bf(v0.x); o[1] = f2bf(v0.y); o[2] = f2bf(v0.z); o[3] = f2bf(v0.w);
    o[4] = f2bf(v1.x); o[5] = f2bf(v1.y); o[6] = f2bf(v1.z); o[7] = f2bf(v1.w);
    *(u16x8*)&Y[i ^ (row7 << 3)] = o;
}

// ---------------------------------------------------------------------------
// transpose + convert: W f32 [K][N] -> WT bf16 [N][K], swizzled (slot ^= n&7).
// ---------------------------------------------------------------------------
__global__ __launch_bounds__(256) void transpose_f32_bf16(
    const float* __restrict__ W, unsigned short* __restrict__ WT, int K, int N)
{
    constexpr int LDT = 66;
    __shared__ unsigned short t_lds[64 * LDT];
    const int kt = blockIdx.x * 64, nt = blockIdx.y * 64;
    const int tid = threadIdx.x;
    const int c = (tid & 15) * 4;
    #pragma unroll
    for (int p = 0; p < 4; ++p) {
        const int r = p * 16 + (tid >> 4);
        float4 v = *(const float4*)&W[(size_t)(kt + r) * N + nt + c];
        u16x2 h0, h1;
        h0[0] = f2bf(v.x); h0[1] = f2bf(v.y);
        h1[0] = f2bf(v.z); h1[1] = f2bf(v.w);
        *(u16x2*)&t_lds[r * LDT + c] = h0;
        *(u16x2*)&t_lds[r * LDT + c + 2] = h1;
    }
    __syncthreads();
    const int kc = (tid & 7) * 8;
    #pragma unroll
    for (int p = 0; p < 2; ++p) {
        const int n = p * 32 + (tid >> 3);
        u16x8 o;
        #pragma unroll
        for (int j = 0; j < 8; ++j) o[j] = t_lds[(kc + j) * LDT + n];
        *(u16x8*)&WT[(size_t)(nt + n) * K + kt + (kc ^ ((n & 7) << 3))] = o;
    }
}

// ---------------------------------------------------------------------------
// Pipelined GEMM: C[M,N] = A[M,K] * B^T, A/B bf16 K-major, sources
// pre-swizzled (slot ^= row&7 per 64-halfword k-block). 128x256 tile, BK=64,
// 8 waves (2Mx4N of 64x64), double-buffered LDS, counted vmcnt (never 0 in
// loop), raw barriers, swizzled ds_reads (2-way conflicts only).
// CMODE 0: C[M][N] normal. CMODE 2: KV split — cols<1024 -> C[M][1024],
// cols>=1024 -> C2[(col-1024)][2048] transposed.
// ---------------------------------------------------------------------------
template <typename CT, int CMODE>
__global__ __launch_bounds__(512) void gemm8(
    const unsigned short* __restrict__ A, const unsigned short* __restrict__ B,
    CT* __restrict__ C, CT* __restrict__ C2, int M, int N, int K)
{
    __shared__ __attribute__((aligned(16))) unsigned short a_lds[2 * 128 * 64];
    __shared__ __attribute__((aligned(16))) unsigned short b_lds[2 * 256 * 64];

    const int bm0 = blockIdx.y * 128, bn0 = blockIdx.x * 256;
    const int tid = threadIdx.x, lane = tid & 63, wid = tid >> 6;
    const int wr = wid >> 2, wc = wid & 3;
    const int l15 = lane & 15, koff = (lane >> 4) * 8;
    const int sw = (l15 & 7) << 3;

    f32x4 acc[4][4] = {};

    // staging sources: verbatim 16B/lane copy (data already pre-swizzled)
    const unsigned short* ag[2];
    const unsigned short* bg[4];
    #pragma unroll
    for (int p = 0; p < 2; ++p) {
        const int row = (wid + p * 8) * 8 + (lane >> 3);
        ag[p] = A + (size_t)(bm0 + row) * K + (lane & 7) * 8;
    }
    #pragma unroll
    for (int p = 0; p < 4; ++p) {
        const int row = (wid + p * 8) * 8 + (lane >> 3);
        bg[p] = B + (size_t)(bn0 + row) * K + (lane & 7) * 8;
    }

    const int nt = K >> 6;

    auto stage = [&](int bf, int t) {
        const int kt = t << 6;
        unsigned short* ab = a_lds + bf * (128 * 64);
        unsigned short* bb = b_lds + bf * (256 * 64);
        #pragma unroll
        for (int p = 0; p < 2; ++p)
            gload16(ag[p] + kt, ab + (wid + p * 8) * 512);
        #pragma unroll
        for (int p = 0; p < 4; ++p)
            gload16(bg[p] + kt, bb + (wid + p * 8) * 512);
    };

    stage(0, 0);
    stage(1, 1);
    WAITVM(6);
    bar();

    for (int t = 0; t < nt; ++t) {
        const int bf = t & 1;
        const unsigned short* ab = a_lds + bf * (128 * 64);
        const unsigned short* bb = b_lds + bf * (256 * 64);
        #pragma unroll
        for (int kk = 0; kk < 2; ++kk) {
            const int cb = (kk * 32 + koff) ^ sw;
            u16x8 af[4], bfr[4];
            #pragma unroll
            for (int i = 0; i < 4; ++i)
                af[i] = *(const u16x8*)&ab[(wr * 64 + i * 16 + l15) * 64 + cb];
            #pragma unroll
            for (int j = 0; j < 4; ++j)
                bfr[j] = *(const u16x8*)&bb[(wc * 64 + j * 16 + l15) * 64 + cb];
            __builtin_amdgcn_s_setprio(1);
            #pragma unroll
            for (int i = 0; i < 4; ++i)
                #pragma unroll
                for (int j = 0; j < 4; ++j)
                    acc[i][j] = MFMA16(af[i], bfr[j], acc[i][j]);
            __builtin_amdgcn_s_setprio(0);
        }
        bar();                       // all waves done reading buf bf
        if (t + 2 < nt) {
            stage(bf, t + 2);        // overwrite just-consumed buffer
            WAITVM(6);               // own t+1 loads retired (t+2 in flight)
        } else {
            WAITVM(0);
        }
        bar();                       // buf[(t+1)&1] ready for all waves
    }

    #pragma unroll
    for (int i = 0; i < 4; ++i)
        #pragma unroll
        for (int r = 0; r < 4; ++r) {
            const int row = bm0 + wr * 64 + i * 16 + (lane >> 4) * 4 + r;
            if constexpr (CMODE == 0) {
                size_t base = (size_t)row * N + bn0 + wc * 64 + l15;
                #pragma unroll
                for (int j = 0; j < 4; ++j)
                    storeC(acc[i][j][r], &C[base + j * 16]);
            } else {
                #pragma unroll
                for (int j = 0; j < 4; ++j) {
                    const int col = bn0 + wc * 64 + l15 + j * 16;
                    if (col < 1024)
                        storeC(acc[i][j][r], &C[(size_t)row * 1024 + col]);
                    else
                        storeC(acc[i][j][r], &C2[(size_t)(col - 1024) * 2048 + row]);
                }
            }
        }
}

// ---------------------------------------------------------------------------
// Fused RoPE + RMSNorm, in-place on bf16 [S][H*128].
// ---------------------------------------------------------------------------
__global__ void rope_rmsnorm(unsigned short* __restrict__ X,
                             const int* __restrict__ pos_ids,
                             const float* __restrict__ W, int H, float outscale)
{
    const int s = blockIdx.x;
    const int tid = threadIdx.x;
    const int h = tid >> 3, t8 = tid & 7;
    const int rowstride = H * 128;
    unsigned short* p = X + (size_t)s * rowstride + h * 128 + t8 * 8;
    u16x8 lo = *(u16x8*)p;
    u16x8 hi = *(u16x8*)(p + 64);
    const float fpos = (float)pos_ids[s];
    float na[8], nb[8];
    float ss = 0.f;
    #pragma unroll
    for (int j = 0; j < 8; ++j) {
        const int d = t8 * 8 + j;
        float inv = expf(-0.14391156831212787f * (float)d);
        float fr = fpos * inv;
        float c = cosf(fr), sn = sinf(fr);
        float a = bf2f(lo[j]), b = bf2f(hi[j]);
        na[j] = a * c - b * sn;
        nb[j] = b * c + a * sn;
        ss += na[j] * na[j] + nb[j] * nb[j];
    }
    ss += __shfl_xor(ss, 1, 8);
    ss += __shfl_xor(ss, 2, 8);
    ss += __shfl_xor(ss, 4, 8);
    const float rn = rsqrtf(ss * (1.0f / 128.0f) + 1e-6f) * outscale;
    #pragma unroll
    for (int j = 0; j < 8; ++j) {
        const int d = t8 * 8 + j;
        lo[j] = f2bf(na[j] * rn * W[d]);
        hi[j] = f2bf(nb[j] * rn * W[d + 64]);
    }
    *(u16x8*)p = lo;
    *(u16x8*)(p + 64) = hi;
}

// ---------------------------------------------------------------------------
// Causal flash attention, V^T input, bf16 output (written st-swizzled so the
// O-projection GEMM can consume it as a pre-swizzled A operand).
// ---------------------------------------------------------------------------
__global__ __launch_bounds__(256, 2) void attn_kernel(
    const unsigned short* __restrict__ Q, const unsigned short* __restrict__ K,
    const unsigned short* __restrict__ VT, unsigned short* __restrict__ O)
{
    constexpr int LDK = 136, LDV = 72, LDP = 72;
    __shared__ __attribute__((aligned(16))) unsigned short k_lds[64 * LDK];
    __shared__ __attribute__((aligned(16))) unsigned short v_lds[128 * LDV];
    __shared__ __attribute__((aligned(16))) unsigned short p_lds[4 * 2 * 16 * LDP];

    const int bid = blockIdx.x;
    const int h = bid & 31;
    const int qp = bid >> 5;
    const int qb = qp < 8 ? qp : 23 - qp;
    const int q0 = qb * 128;
    const int kvh = h >> 2;
    const int tid = threadIdx.x, lane = tid & 63, wid = tid >> 6;
    const int l15 = lane & 15, koff = (lane >> 4) * 8;
    const int qw = q0 + wid * 32;

    u16x8 qf[2][4];
    #pragma unroll
    for (int qt = 0; qt < 2; ++qt)
        #pragma unroll
        for (int kk = 0; kk < 4; ++kk)
            qf[qt][kk] = *(const u16x8*)&Q[(size_t)(qw + qt * 16 + l15) * 4096 +
                                           h * 128 + kk * 32 + koff];

    f32x4 o_acc[2][8] = {};
    float m_r[2][4], l_r[2][4];
    #pragma unroll
    for (int qt = 0; qt < 2; ++qt)
        #pragma unroll
        for (int r = 0; r < 4; ++r) { m_r[qt][r] = -1e30f; l_r[qt][r] = 0.f; }

    const int kr = tid >> 2, kd = (tid & 3) * 32;
    const int vr = tid >> 1, vc = (tid & 1) * 32;
    const unsigned short* kg = K + (size_t)kvh * 128 + kd;
    const unsigned short* vg = VT + (size_t)(kvh * 128 + vr) * 2048 + vc;

    const int nchunk = qb * 2 + 2;
    u16x8 kst[4], vst[4];
    #pragma unroll
    for (int j = 0; j < 4; ++j) {
        kst[j] = *(const u16x8*)&kg[(size_t)kr * 1024 + j * 8];
        vst[j] = *(const u16x8*)&vg[j * 8];
    }

    for (int ch = 0; ch < nchunk; ++ch) {
        const int kv0 = ch * 64;
        __syncthreads();
        #pragma unroll
        for (int j = 0; j < 4; ++j) {
            *(u16x8*)&k_lds[kr * LDK + kd + j * 8] = kst[j];
            *(u16x8*)&v_lds[vr * LDV + vc + j * 8] = vst[j];
        }
        __syncthreads();
        if (ch + 1 < nchunk) {
            const int kv1 = kv0 + 64;
            #pragma unroll
            for (int j = 0; j < 4; ++j) {
                kst[j] = *(const u16x8*)&kg[(size_t)(kv1 + kr) * 1024 + j * 8];
                vst[j] = *(const u16x8*)&vg[kv1 + j * 8];
            }
        }

        if (kv0 <= qw + 31) {
            f32x4 sacc[2][4] = {};
            #pragma unroll
            for (int kk = 0; kk < 4; ++kk)
                #pragma unroll
                for (int jt = 0; jt < 4; ++jt) {
                    u16x8 kf = *(u16x8*)&k_lds[(jt * 16 + l15) * LDK + kk * 32 + koff];
                    #pragma unroll
                    for (int qt = 0; qt < 2; ++qt)
                        sacc[qt][jt] = MFMA16(qf[qt][kk], kf, sacc[qt][jt]);
                }

            #pragma unroll
            for (int qt = 0; qt < 2; ++qt) {
                const int rbase = qw + qt * 16 + (lane >> 4) * 4;
                #pragma unroll
                for (int jt = 0; jt < 4; ++jt)
                    #pragma unroll
                    for (int r = 0; r < 4; ++r)
                        if (kv0 + jt * 16 + l15 > rbase + r) sacc[qt][jt][r] = -1e9f;
                float alpha[4];
                #pragma unroll
                for (int r = 0; r < 4; ++r) {
                    float mx = fmaxf(fmaxf(sacc[qt][0][r], sacc[qt][1][r]),
                                     fmaxf(sacc[qt][2][r], sacc[qt][3][r]));
                    mx = fmaxf(mx, __shfl_xor(mx, 1, 16));
                    mx = fmaxf(mx, __shfl_xor(mx, 2, 16));
                    mx = fmaxf(mx, __shfl_xor(mx, 4, 16));
                    mx = fmaxf(mx, __shfl_xor(mx, 8, 16));
                    float mnew = fmaxf(m_r[qt][r], mx);
                    alpha[r] = __expf(m_r[qt][r] - mnew);
                    m_r[qt][r] = mnew;
                }
                #pragma unroll
                for (int jt = 0; jt < 4; ++jt)
                    #pragma unroll
                    for (int r = 0; r < 4; ++r)
                        sacc[qt][jt][r] = __expf(sacc[qt][jt][r] - m_r[qt][r]);
                #pragma unroll
                for (int r = 0; r < 4; ++r) {
                    float ps = (sacc[qt][0][r] + sacc[qt][1][r]) +
                               (sacc[qt][2][r] + sacc[qt][3][r]);
                    ps += __shfl_xor(ps, 1, 16);
                    ps += __shfl_xor(ps, 2, 16);
                    ps += __shfl_xor(ps, 4, 16);
                    ps += __shfl_xor(ps, 8, 16);
                    l_r[qt][r] = l_r[qt][r] * alpha[r] + ps;
                }
                #pragma unroll
                for (int nt = 0; nt < 8; ++nt)
                    #pragma unroll
                    for (int r = 0; r < 4; ++r) o_acc[qt][nt][r] *= alpha[r];
                const int pb = ((wid * 2 + qt) * 16) * LDP;
                #pragma unroll
                for (int jt = 0; jt < 4; ++jt)
                    #pragma unroll
                    for (int r = 0; r < 4; ++r)
                        p_lds[pb + ((lane >> 4) * 4 + r) * LDP + jt * 16 + l15] =
                            f2bf(sacc[qt][jt][r]);
            }

            u16x8 pf[2][2];
            #pragma unroll
            for (int qt = 0; qt < 2; ++qt)
                #pragma unroll
                for (int ks = 0; ks < 2; ++ks)
                    pf[qt][ks] = *(u16x8*)&p_lds[((wid * 2 + qt) * 16 + l15) * LDP +
                                                 ks * 32 + koff];
            #pragma unroll
            for (int nt = 0; nt < 8; ++nt)
                #pragma unroll
                for (int ks = 0; ks < 2; ++ks) {
                    u16x8 vf = *(u16x8*)&v_lds[(nt * 16 + l15) * LDV + ks * 32 + koff];
                    #pragma unroll
                    for (int qt = 0; qt < 2; ++qt)
                        o_acc[qt][nt] = MFMA16(pf[qt][ks], vf, o_acc[qt][nt]);
                }
        }
    }

    #pragma unroll
    for (int qt = 0; qt < 2; ++qt)
        #pragma unroll
        for (int r = 0; r < 4; ++r) {
            float inv_l = 1.0f / l_r[qt][r];
            int row = qw + qt * 16 + (lane >> 4) * 4 + r;
            const int r7s = (row & 7) << 3;
            #pragma unroll
            for (int nt = 0; nt < 8; ++nt) {
                int col = h * 128 + nt * 16 + l15;
                O[(size_t)row * 4096 + (col ^ r7s)] =
                    f2bf(o_acc[qt][nt][r] * inv_l);
            }
        }
}

// ---------------------------------------------------------------------------
extern "C" void kernel_launch(void* const* d_in, const int* in_sizes, int n_in,
                              void* d_out, int out_size, void* d_ws, size_t ws_size,
                              hipStream_t stream)
{
    (void)in_sizes; (void)n_in; (void)out_size; (void)ws_size;
    const float* hidden = (const float*)d_in[0];
    const float* wq     = (const float*)d_in[1];
    const float* wk     = (const float*)d_in[2];
    const float* wv     = (const float*)d_in[3];
    const float* wo     = (const float*)d_in[4];
    const float* qnw    = (const float*)d_in[5];
    const float* knw    = (const float*)d_in[6];
    const int*   pos    = (const int*)d_in[8];
    float* out = (float*)d_out;

    const size_t MB = 1024 * 1024;
    char* ws = (char*)d_ws;
    unsigned short* q_ws  = (unsigned short*)(ws);             // 16 MB  [2048][4096]
    unsigned short* k_ws  = (unsigned short*)(ws + 16 * MB);   //  4 MB  [2048][1024]
    unsigned short* vt_ws = (unsigned short*)(ws + 20 * MB);   //  4 MB  [1024][2048]
    unsigned short* hb    = (unsigned short*)(ws + 24 * MB);   // 16 MB  hidden bf16 (swz)
    unsigned short* a_ws  = hb;                                // reuse: attn out (swz)
    unsigned short* wqt   = (unsigned short*)(ws + 40 * MB);   // 32 MB  [4096][4096] swz
    unsigned short* wkt   = (unsigned short*)(ws + 72 * MB);   //  8 MB  [1024][4096] swz
    unsigned short* wvt   = (unsigned short*)(ws + 80 * MB);   //  8 MB  [1024][4096] swz (contiguous after wkt)
    unsigned short* wot   = (unsigned short*)(ws + 88 * MB);   // 32 MB  [4096][4096] swz

    convert_f32_bf16_swz<<<4096, 256, 0, stream>>>(hidden, hb);
    transpose_f32_bf16<<<dim3(64, 64), 256, 0, stream>>>(wq, wqt, 4096, 4096);
    transpose_f32_bf16<<<dim3(64, 16), 256, 0, stream>>>(wk, wkt, 4096, 1024);
    transpose_f32_bf16<<<dim3(64, 16), 256, 0, stream>>>(wv, wvt, 4096, 1024);
    transpose_f32_bf16<<<dim3(64, 64), 256, 0, stream>>>(wo, wot, 4096, 4096);

    gemm8<unsigned short, 0><<<dim3(16, 16), 512, 0, stream>>>(
        hb, wqt, q_ws, (unsigned short*)nullptr, 2048, 4096, 4096);
    gemm8<unsigned short, 2><<<dim3(8, 16), 512, 0, stream>>>(
        hb, wkt, k_ws, vt_ws, 2048, 2048, 4096);

    rope_rmsnorm<<<2048, 256, 0, stream>>>(q_ws, pos, qnw, 32, 0.08838834764831845f);
    rope_rmsnorm<<<2048, 64, 0, stream>>>(k_ws, pos, knw, 8, 1.0f);

    attn_kernel<<<512, 256, 0, stream>>>(q_ws, k_ws, vt_ws, a_ws);

    gemm8<float, 0><<<dim3(16, 16), 512, 0, stream>>>(
        a_ws, wot, out, (float*)nullptr, 2048, 4096, 4096);
}

// Round 5
// 429.288 us; speedup vs baseline: 1.9731x; 1.0662x over previous
//
#include <hip/hip_runtime.h>

typedef __bf16 bf16x8 __attribute__((ext_vector_type(8)));
typedef float f32x4 __attribute__((ext_vector_type(4)));
typedef unsigned short u16x8 __attribute__((ext_vector_type(8)));
typedef unsigned short u16x4 __attribute__((ext_vector_type(4)));
typedef unsigned short u16x2 __attribute__((ext_vector_type(2)));

__device__ inline unsigned short f2bf(float f) {
    return __builtin_bit_cast(unsigned short, (__bf16)f);
}
__device__ inline float bf2f(unsigned short u) {
    return (float)__builtin_bit_cast(__bf16, u);
}

__device__ inline void storeC(float v, float* p) { *p = v; }
__device__ inline void storeC(float v, unsigned short* p) { *p = f2bf(v); }

#define MFMA16(a, b, c) __builtin_amdgcn_mfma_f32_16x16x32_bf16( \
    __builtin_bit_cast(bf16x8, a), __builtin_bit_cast(bf16x8, b), (c), 0, 0, 0)

// async global->LDS, 16B per lane; LDS dest = wave-uniform base + lane*16
__device__ inline void gload16(const unsigned short* g, unsigned short* l) {
    __builtin_amdgcn_global_load_lds(
        (const __attribute__((address_space(1))) unsigned int*)(g),
        (__attribute__((address_space(3))) unsigned int*)(l), 16, 0, 0);
}

__device__ __forceinline__ void bar() {
    asm volatile("" ::: "memory");
    __builtin_amdgcn_s_barrier();
    asm volatile("" ::: "memory");
}
#define WAITVM(N) asm volatile("s_waitcnt vmcnt(" #N ")" ::: "memory")

// ---------------------------------------------------------------------------
// convert f32 -> bf16, writing st-swizzled rows (slot ^= row&7 within each
// 64-halfword k-block). Row length hardcoded 4096 (hidden).
// ---------------------------------------------------------------------------
__global__ __launch_bounds__(256) void convert_f32_bf16_swz(
    const float* __restrict__ X, unsigned short* __restrict__ Y)
{
    const size_t i = ((size_t)blockIdx.x * 256 + threadIdx.x) * 8;
    const size_t row7 = (i >> 12) & 7;
    float4 v0 = *(const float4*)&X[i];
    float4 v1 = *(const float4*)&X[i + 4];
    u16x8 o;
    o[0] = f2bf(v0.x); o[1] = f2bf(v0.y); o[2] = f2bf(v0.z); o[3] = f2bf(v0.w);
    o[4] = f2bf(v1.x); o[5] = f2bf(v1.y); o[6] = f2bf(v1.z); o[7] = f2bf(v1.w);
    *(u16x8*)&Y[i ^ (row7 << 3)] = o;
}

// ---------------------------------------------------------------------------
// transpose + convert: W f32 [K][N] -> WT bf16 [N][K], swizzled (slot ^= n&7).
// ---------------------------------------------------------------------------
__global__ __launch_bounds__(256) void transpose_f32_bf16(
    const float* __restrict__ W, unsigned short* __restrict__ WT, int K, int N)
{
    constexpr int LDT = 66;
    __shared__ unsigned short t_lds[64 * LDT];
    const int kt = blockIdx.x * 64, nt = blockIdx.y * 64;
    const int tid = threadIdx.x;
    const int c = (tid & 15) * 4;
    #pragma unroll
    for (int p = 0; p < 4; ++p) {
        const int r = p * 16 + (tid >> 4);
        float4 v = *(const float4*)&W[(size_t)(kt + r) * N + nt + c];
        u16x2 h0, h1;
        h0[0] = f2bf(v.x); h0[1] = f2bf(v.y);
        h1[0] = f2bf(v.z); h1[1] = f2bf(v.w);
        *(u16x2*)&t_lds[r * LDT + c] = h0;
        *(u16x2*)&t_lds[r * LDT + c + 2] = h1;
    }
    __syncthreads();
    const int kc = (tid & 7) * 8;
    #pragma unroll
    for (int p = 0; p < 2; ++p) {
        const int n = p * 32 + (tid >> 3);
        u16x8 o;
        #pragma unroll
        for (int j = 0; j < 8; ++j) o[j] = t_lds[(kc + j) * LDT + n];
        *(u16x8*)&WT[(size_t)(nt + n) * K + kt + (kc ^ ((n & 7) << 3))] = o;
    }
}

// ---------------------------------------------------------------------------
// Pipelined GEMM: C[M,N] = A[M,K] * B^T, A/B bf16 K-major, sources
// pre-swizzled (slot ^= row&7 per 64-halfword k-block). 128x256 tile, BK=64,
// 8 waves (2Mx4N of 64x64), double-buffered LDS, counted vmcnt.
// CMODE 0: C[M][N] normal. CMODE 2: KV split — cols<1024 -> C[M][1024],
// cols>=1024 -> C2[(col-1024)][2048] transposed.
// ---------------------------------------------------------------------------
template <typename CT, int CMODE>
__global__ __launch_bounds__(512) void gemm8(
    const unsigned short* __restrict__ A, const unsigned short* __restrict__ B,
    CT* __restrict__ C, CT* __restrict__ C2, int M, int N, int K)
{
    __shared__ __attribute__((aligned(16))) unsigned short a_lds[2 * 128 * 64];
    __shared__ __attribute__((aligned(16))) unsigned short b_lds[2 * 256 * 64];

    const int bm0 = blockIdx.y * 128, bn0 = blockIdx.x * 256;
    const int tid = threadIdx.x, lane = tid & 63, wid = tid >> 6;
    const int wr = wid >> 2, wc = wid & 3;
    const int l15 = lane & 15, koff = (lane >> 4) * 8;
    const int sw = (l15 & 7) << 3;

    f32x4 acc[4][4] = {};

    const unsigned short* ag[2];
    const unsigned short* bg[4];
    #pragma unroll
    for (int p = 0; p < 2; ++p) {
        const int row = (wid + p * 8) * 8 + (lane >> 3);
        ag[p] = A + (size_t)(bm0 + row) * K + (lane & 7) * 8;
    }
    #pragma unroll
    for (int p = 0; p < 4; ++p) {
        const int row = (wid + p * 8) * 8 + (lane >> 3);
        bg[p] = B + (size_t)(bn0 + row) * K + (lane & 7) * 8;
    }

    const int nt = K >> 6;

    auto stage = [&](int bf, int t) {
        const int kt = t << 6;
        unsigned short* ab = a_lds + bf * (128 * 64);
        unsigned short* bb = b_lds + bf * (256 * 64);
        #pragma unroll
        for (int p = 0; p < 2; ++p)
            gload16(ag[p] + kt, ab + (wid + p * 8) * 512);
        #pragma unroll
        for (int p = 0; p < 4; ++p)
            gload16(bg[p] + kt, bb + (wid + p * 8) * 512);
    };

    stage(0, 0);
    stage(1, 1);
    WAITVM(6);
    bar();

    for (int t = 0; t < nt; ++t) {
        const int bf = t & 1;
        const unsigned short* ab = a_lds + bf * (128 * 64);
        const unsigned short* bb = b_lds + bf * (256 * 64);
        #pragma unroll
        for (int kk = 0; kk < 2; ++kk) {
            const int cb = (kk * 32 + koff) ^ sw;
            u16x8 af[4], bfr[4];
            #pragma unroll
            for (int i = 0; i < 4; ++i)
                af[i] = *(const u16x8*)&ab[(wr * 64 + i * 16 + l15) * 64 + cb];
            #pragma unroll
            for (int j = 0; j < 4; ++j)
                bfr[j] = *(const u16x8*)&bb[(wc * 64 + j * 16 + l15) * 64 + cb];
            __builtin_amdgcn_s_setprio(1);
            #pragma unroll
            for (int i = 0; i < 4; ++i)
                #pragma unroll
                for (int j = 0; j < 4; ++j)
                    acc[i][j] = MFMA16(af[i], bfr[j], acc[i][j]);
            __builtin_amdgcn_s_setprio(0);
        }
        bar();
        if (t + 2 < nt) {
            stage(bf, t + 2);
            WAITVM(6);
        } else {
            WAITVM(0);
        }
        bar();
    }

    #pragma unroll
    for (int i = 0; i < 4; ++i)
        #pragma unroll
        for (int r = 0; r < 4; ++r) {
            const int row = bm0 + wr * 64 + i * 16 + (lane >> 4) * 4 + r;
            if constexpr (CMODE == 0) {
                size_t base = (size_t)row * N + bn0 + wc * 64 + l15;
                #pragma unroll
                for (int j = 0; j < 4; ++j)
                    storeC(acc[i][j][r], &C[base + j * 16]);
            } else {
                #pragma unroll
                for (int j = 0; j < 4; ++j) {
                    const int col = bn0 + wc * 64 + l15 + j * 16;
                    if (col < 1024)
                        storeC(acc[i][j][r], &C[(size_t)row * 1024 + col]);
                    else
                        storeC(acc[i][j][r], &C2[(size_t)(col - 1024) * 2048 + row]);
                }
            }
        }
}

// ---------------------------------------------------------------------------
// Fused RoPE + RMSNorm, in-place on bf16 [S][H*128].
// ---------------------------------------------------------------------------
__global__ void rope_rmsnorm(unsigned short* __restrict__ X,
                             const int* __restrict__ pos_ids,
                             const float* __restrict__ W, int H, float outscale)
{
    const int s = blockIdx.x;
    const int tid = threadIdx.x;
    const int h = tid >> 3, t8 = tid & 7;
    const int rowstride = H * 128;
    unsigned short* p = X + (size_t)s * rowstride + h * 128 + t8 * 8;
    u16x8 lo = *(u16x8*)p;
    u16x8 hi = *(u16x8*)(p + 64);
    const float fpos = (float)pos_ids[s];
    float na[8], nb[8];
    float ss = 0.f;
    #pragma unroll
    for (int j = 0; j < 8; ++j) {
        const int d = t8 * 8 + j;
        float inv = expf(-0.14391156831212787f * (float)d);
        float fr = fpos * inv;
        float c = cosf(fr), sn = sinf(fr);
        float a = bf2f(lo[j]), b = bf2f(hi[j]);
        na[j] = a * c - b * sn;
        nb[j] = b * c + a * sn;
        ss += na[j] * na[j] + nb[j] * nb[j];
    }
    ss += __shfl_xor(ss, 1, 8);
    ss += __shfl_xor(ss, 2, 8);
    ss += __shfl_xor(ss, 4, 8);
    const float rn = rsqrtf(ss * (1.0f / 128.0f) + 1e-6f) * outscale;
    #pragma unroll
    for (int j = 0; j < 8; ++j) {
        const int d = t8 * 8 + j;
        lo[j] = f2bf(na[j] * rn * W[d]);
        hi[j] = f2bf(nb[j] * rn * W[d + 64]);
    }
    *(u16x8*)p = lo;
    *(u16x8*)(p + 64) = hi;
}

// ---------------------------------------------------------------------------
// Causal flash attention, V^T input, bf16 output (written st-swizzled so the
// O-projection GEMM can consume it as a pre-swizzled A operand).
// Swapped QK^T (mfma(K,Q) -> S^T): softmax is lane-local (q = lane&15),
// row-reduce = 2 shfls. Defer-rescale (THR=8). Packed b64 P-writes.
// Grid: bid&7 = kv-head (XCD L2 affinity), heavy q-blocks first.
// ---------------------------------------------------------------------------
__global__ __launch_bounds__(256, 2) void attn_kernel(
    const unsigned short* __restrict__ Q, const unsigned short* __restrict__ K,
    const unsigned short* __restrict__ VT, unsigned short* __restrict__ O)
{
    constexpr int LDK = 136, LDV = 72, LDP = 72;
    __shared__ __attribute__((aligned(16))) unsigned short k_lds[64 * LDK];
    __shared__ __attribute__((aligned(16))) unsigned short v_lds[128 * LDV];
    __shared__ __attribute__((aligned(16))) unsigned short p_lds[4 * 32 * LDP];

    const int bid = blockIdx.x;
    const int kvh = bid & 7;            // XCD x serves kv-head x
    const int rest = bid >> 3;
    const int h = kvh * 4 + (rest & 3);
    const int qb = 15 - (rest >> 2);    // heavy blocks dispatched first
    const int q0 = qb * 128;
    const int tid = threadIdx.x, lane = tid & 63, wid = tid >> 6;
    const int l15 = lane & 15, g4 = (lane >> 4) * 4, koff = (lane >> 4) * 8;
    const int qw = q0 + wid * 32;

    u16x8 qf[2][4];
    #pragma unroll
    for (int qt = 0; qt < 2; ++qt)
        #pragma unroll
        for (int kk = 0; kk < 4; ++kk)
            qf[qt][kk] = *(const u16x8*)&Q[(size_t)(qw + qt * 16 + l15) * 4096 +
                                           h * 128 + kk * 32 + koff];

    f32x4 o_acc[2][8] = {};
    float m_r[2] = {-1e30f, -1e30f}, l_r[2] = {0.f, 0.f};

    const int kr = tid >> 2, kd = (tid & 3) * 32;
    const int vr = tid >> 1, vc = (tid & 1) * 32;
    const unsigned short* kg = K + (size_t)kvh * 128 + kd;
    const unsigned short* vg = VT + (size_t)(kvh * 128 + vr) * 2048 + vc;

    const int nchunk = qb * 2 + 2;
    u16x8 kst[4], vst[4];
    #pragma unroll
    for (int j = 0; j < 4; ++j) {
        kst[j] = *(const u16x8*)&kg[(size_t)kr * 1024 + j * 8];
        vst[j] = *(const u16x8*)&vg[j * 8];
    }

    for (int ch = 0; ch < nchunk; ++ch) {
        const int kv0 = ch * 64;
        __syncthreads();
        #pragma unroll
        for (int j = 0; j < 4; ++j) {
            *(u16x8*)&k_lds[kr * LDK + kd + j * 8] = kst[j];
            *(u16x8*)&v_lds[vr * LDV + vc + j * 8] = vst[j];
        }
        __syncthreads();
        if (ch + 1 < nchunk) {
            const int kv1 = kv0 + 64;
            #pragma unroll
            for (int j = 0; j < 4; ++j) {
                kst[j] = *(const u16x8*)&kg[(size_t)(kv1 + kr) * 1024 + j * 8];
                vst[j] = *(const u16x8*)&vg[kv1 + j * 8];
            }
        }

        if (kv0 <= qw + 31) {
            // ---- QK^T swapped: sacc[qt][jt] = S^T tile, lane's q = l15,
            //      keys = kv0 + jt*16 + g4 + r
            f32x4 sacc[2][4] = {};
            #pragma unroll
            for (int kk = 0; kk < 4; ++kk)
                #pragma unroll
                for (int jt = 0; jt < 4; ++jt) {
                    u16x8 kf = *(u16x8*)&k_lds[(jt * 16 + l15) * LDK + kk * 32 + koff];
                    #pragma unroll
                    for (int qt = 0; qt < 2; ++qt)
                        sacc[qt][jt] = MFMA16(kf, qf[qt][kk], sacc[qt][jt]);
                }

            const bool needmask = (kv0 + 63 > qw);
            #pragma unroll
            for (int qt = 0; qt < 2; ++qt) {
                const int q = qw + qt * 16 + l15;
                if (needmask) {
                    #pragma unroll
                    for (int jt = 0; jt < 4; ++jt)
                        #pragma unroll
                        for (int r = 0; r < 4; ++r)
                            if (kv0 + jt * 16 + g4 + r > q) sacc[qt][jt][r] = -1e9f;
                }
                // lane-local row max
                float pmax = sacc[qt][0][0];
                #pragma unroll
                for (int jt = 0; jt < 4; ++jt)
                    #pragma unroll
                    for (int r = 0; r < 4; ++r)
                        pmax = fmaxf(pmax, sacc[qt][jt][r]);
                pmax = fmaxf(pmax, __shfl_xor(pmax, 16));
                pmax = fmaxf(pmax, __shfl_xor(pmax, 32));
                // defer-rescale (THR=8)
                if (__any(pmax > m_r[qt] + 8.0f)) {
                    float mnew = fmaxf(m_r[qt], pmax);
                    float alpha = __expf(m_r[qt] - mnew);
                    m_r[qt] = mnew;
                    l_r[qt] *= alpha;
                    float arow[4];
                    #pragma unroll
                    for (int r = 0; r < 4; ++r)
                        arow[r] = __shfl(alpha, g4 + r, 16);
                    #pragma unroll
                    for (int nt = 0; nt < 8; ++nt)
                        #pragma unroll
                        for (int r = 0; r < 4; ++r)
                            o_acc[qt][nt][r] *= arow[r];
                }
                // exp + lane-local sum
                float ps = 0.f;
                #pragma unroll
                for (int jt = 0; jt < 4; ++jt)
                    #pragma unroll
                    for (int r = 0; r < 4; ++r) {
                        float e = __expf(sacc[qt][jt][r] - m_r[qt]);
                        sacc[qt][jt][r] = e;
                        ps += e;
                    }
                ps += __shfl_xor(ps, 16);
                ps += __shfl_xor(ps, 32);
                l_r[qt] += ps;
                // packed P write: row = q, cols jt*16+g4 .. +3
                const int prow = (wid * 32 + qt * 16 + l15) * LDP;
                #pragma unroll
                for (int jt = 0; jt < 4; ++jt) {
                    u16x4 w;
                    #pragma unroll
                    for (int r = 0; r < 4; ++r) w[r] = f2bf(sacc[qt][jt][r]);
                    *(u16x4*)&p_lds[prow + jt * 16 + g4] = w;
                }
            }

            // ---- PV: O[32 q][128 d] += P[32][64] * V[64][128]
            u16x8 pf[2][2];
            #pragma unroll
            for (int qt = 0; qt < 2; ++qt)
                #pragma unroll
                for (int ks = 0; ks < 2; ++ks)
                    pf[qt][ks] = *(u16x8*)&p_lds[(wid * 32 + qt * 16 + l15) * LDP +
                                                 ks * 32 + koff];
            #pragma unroll
            for (int nt = 0; nt < 8; ++nt)
                #pragma unroll
                for (int ks = 0; ks < 2; ++ks) {
                    u16x8 vf = *(u16x8*)&v_lds[(nt * 16 + l15) * LDV + ks * 32 + koff];
                    #pragma unroll
                    for (int qt = 0; qt < 2; ++qt)
                        o_acc[qt][nt] = MFMA16(pf[qt][ks], vf, o_acc[qt][nt]);
                }
        }
    }

    // epilogue: redistribute l to o_acc rows, normalize, store swizzled bf16
    #pragma unroll
    for (int qt = 0; qt < 2; ++qt) {
        float lrow[4];
        #pragma unroll
        for (int r = 0; r < 4; ++r)
            lrow[r] = __shfl(l_r[qt], g4 + r, 16);
        #pragma unroll
        for (int r = 0; r < 4; ++r) {
            float inv_l = 1.0f / lrow[r];
            int row = qw + qt * 16 + g4 + r;
            const int r7s = (row & 7) << 3;
            #pragma unroll
            for (int nt = 0; nt < 8; ++nt) {
                int col = h * 128 + nt * 16 + l15;
                O[(size_t)row * 4096 + (col ^ r7s)] =
                    f2bf(o_acc[qt][nt][r] * inv_l);
            }
        }
    }
}

// ---------------------------------------------------------------------------
extern "C" void kernel_launch(void* const* d_in, const int* in_sizes, int n_in,
                              void* d_out, int out_size, void* d_ws, size_t ws_size,
                              hipStream_t stream)
{
    (void)in_sizes; (void)n_in; (void)out_size; (void)ws_size;
    const float* hidden = (const float*)d_in[0];
    const float* wq     = (const float*)d_in[1];
    const float* wk     = (const float*)d_in[2];
    const float* wv     = (const float*)d_in[3];
    const float* wo     = (const float*)d_in[4];
    const float* qnw    = (const float*)d_in[5];
    const float* knw    = (const float*)d_in[6];
    const int*   pos    = (const int*)d_in[8];
    float* out = (float*)d_out;

    const size_t MB = 1024 * 1024;
    char* ws = (char*)d_ws;
    unsigned short* q_ws  = (unsigned short*)(ws);             // 16 MB  [2048][4096]
    unsigned short* k_ws  = (unsigned short*)(ws + 16 * MB);   //  4 MB  [2048][1024]
    unsigned short* vt_ws = (unsigned short*)(ws + 20 * MB);   //  4 MB  [1024][2048]
    unsigned short* hb    = (unsigned short*)(ws + 24 * MB);   // 16 MB  hidden bf16 (swz)
    unsigned short* a_ws  = hb;                                // reuse: attn out (swz)
    unsigned short* wqt   = (unsigned short*)(ws + 40 * MB);   // 32 MB  [4096][4096] swz
    unsigned short* wkt   = (unsigned short*)(ws + 72 * MB);   //  8 MB  [1024][4096] swz
    unsigned short* wvt   = (unsigned short*)(ws + 80 * MB);   //  8 MB  [1024][4096] swz
    unsigned short* wot   = (unsigned short*)(ws + 88 * MB);   // 32 MB  [4096][4096] swz

    convert_f32_bf16_swz<<<4096, 256, 0, stream>>>(hidden, hb);
    transpose_f32_bf16<<<dim3(64, 64), 256, 0, stream>>>(wq, wqt, 4096, 4096);
    transpose_f32_bf16<<<dim3(64, 16), 256, 0, stream>>>(wk, wkt, 4096, 1024);
    transpose_f32_bf16<<<dim3(64, 16), 256, 0, stream>>>(wv, wvt, 4096, 1024);
    transpose_f32_bf16<<<dim3(64, 64), 256, 0, stream>>>(wo, wot, 4096, 4096);

    gemm8<unsigned short, 0><<<dim3(16, 16), 512, 0, stream>>>(
        hb, wqt, q_ws, (unsigned short*)nullptr, 2048, 4096, 4096);
    gemm8<unsigned short, 2><<<dim3(8, 16), 512, 0, stream>>>(
        hb, wkt, k_ws, vt_ws, 2048, 2048, 4096);

    rope_rmsnorm<<<2048, 256, 0, stream>>>(q_ws, pos, qnw, 32, 0.08838834764831845f);
    rope_rmsnorm<<<2048, 64, 0, stream>>>(k_ws, pos, knw, 8, 1.0f);

    attn_kernel<<<512, 256, 0, stream>>>(q_ws, k_ws, vt_ws, a_ws);

    gemm8<float, 0><<<dim3(16, 16), 512, 0, stream>>>(
        a_ws, wot, out, (float*)nullptr, 2048, 4096, 4096);
}